// Round 1
// baseline (29163.092 us; speedup 1.0000x reference)
//
#include <hip/hip_runtime.h>
#include <cstdint>

#define B_  64
#define T_  4096
#define F_  100
#define H_  200
#define G_  600   // 3H

__device__ __forceinline__ float sigmoidf_(float x) {
    return 1.0f / (1.0f + __expf(-x));
}
__device__ __forceinline__ float tanh_fast_(float x) {
    // tanh(x) = (1 - e^{-2x}) / (1 + e^{-2x}); |x| bounded ~17 here, safe in fp32
    float e = __expf(-2.0f * x);
    return (1.0f - e) / (1.0f + e);
}

// ---------------- Phase 1: gi = x @ Wi + bi ----------------
// grid: (B*TC/64) blocks, 640 threads. Each block: 64 consecutive (b,t) rows x 600 cols.
__global__ __launch_bounds__(640, 1)
void gi_kernel(const float* __restrict__ x, const float* __restrict__ Wi,
               const float* __restrict__ bi, float* __restrict__ gi,
               int t0, int TC) {
    __shared__ float xT[F_ * 68];   // transposed x tile, pad 68 to avoid bank conflicts
    int row0 = blockIdx.x * 64;     // row index within chunk [0, B*TC)
    int b    = row0 / TC;
    int tc0  = row0 - b * TC;
    const float* xrow = x + ((size_t)b * T_ + t0 + tc0) * F_;  // 6400 contiguous floats
    for (int i = threadIdx.x; i < 64 * F_; i += 640) {
        int r = i / F_, f = i - r * F_;
        xT[f * 68 + r] = xrow[i];
    }
    __syncthreads();
    int col = threadIdx.x < G_ ? threadIdx.x : G_ - 1;
    float acc[64];
    #pragma unroll
    for (int r = 0; r < 64; ++r) acc[r] = 0.f;
    for (int f = 0; f < F_; ++f) {
        float wi = Wi[f * G_ + col];                 // coalesced, L2-resident (240 KB)
        const float4* xf = (const float4*)&xT[f * 68];  // broadcast reads
        #pragma unroll
        for (int q = 0; q < 16; ++q) {
            float4 v = xf[q];
            acc[4*q+0] = fmaf(v.x, wi, acc[4*q+0]);
            acc[4*q+1] = fmaf(v.y, wi, acc[4*q+1]);
            acc[4*q+2] = fmaf(v.z, wi, acc[4*q+2]);
            acc[4*q+3] = fmaf(v.w, wi, acc[4*q+3]);
        }
    }
    if (threadIdx.x < G_) {
        float bv = bi[col];
        float* grow = gi + (size_t)row0 * G_ + col;
        #pragma unroll 4
        for (int r = 0; r < 64; ++r) grow[(size_t)r * G_] = acc[r] + bv;  // coalesced per r
    }
}

// ---------------- Phase 2: sequential GRU scan + fused output ----------------
// grid: 64 blocks (one per batch), 640 threads. Thread t owns Wh column t in registers.
__global__ __launch_bounds__(640, 1)
void scan_kernel(const float* __restrict__ gi, const float* __restrict__ Wh,
                 const float* __restrict__ bhn, const float* __restrict__ Wo,
                 const float* __restrict__ bo, float* __restrict__ out,
                 float* __restrict__ hstate, int t0, int TC, int first) {
    __shared__ __align__(16) float h_lds[H_];
    __shared__ float A_lds[G_];    // r,z cols: gi+hh; n cols: gi only
    __shared__ float Hn_lds[H_];   // hh_n + bhn
    int b = blockIdx.x;
    int tid = threadIdx.x;
    int col = tid < G_ ? tid : G_ - 1;

    float wh[H_];                  // one Wh column in registers (200 VGPRs)
    #pragma unroll
    for (int k = 0; k < H_; ++k) wh[k] = Wh[k * G_ + col];   // coalesced
    float bhn_r = (col >= 2*H_) ? bhn[col - 2*H_] : 0.f;

    float hj = 0.f;
    if (tid < H_) {
        hj = first ? 0.f : hstate[b * H_ + tid];
        h_lds[tid] = hj;
    }
    float wo0=0.f, wo1=0.f, wo2=0.f, wo3=0.f, bov=0.f;
    if (tid < 64) {
        wo0 = Wo[tid]; wo1 = Wo[tid+64]; wo2 = Wo[tid+128];
        wo3 = (tid < 8) ? Wo[tid+192] : 0.f;
        bov = bo[0];
    }
    __syncthreads();

    const float* girow = gi + (size_t)b * TC * G_;
    float* outb = out + (size_t)b * T_ + t0;

    for (int tc = 0; tc < TC; ++tc) {
        float g = girow[(size_t)tc * G_ + col];   // issued early; latency hidden by dot
        // hh[col] = dot(h, Wh[:,col]) — h broadcast from LDS, wh in regs
        float acc = 0.f;
        const float4* h4 = (const float4*)h_lds;
        #pragma unroll
        for (int kk = 0; kk < H_/4; ++kk) {
            float4 hv = h4[kk];
            acc = fmaf(hv.x, wh[4*kk+0], acc);
            acc = fmaf(hv.y, wh[4*kk+1], acc);
            acc = fmaf(hv.z, wh[4*kk+2], acc);
            acc = fmaf(hv.w, wh[4*kk+3], acc);
        }
        if (tid < G_) {
            if (col < 2*H_) {
                A_lds[col] = g + acc;
            } else {
                A_lds[col] = g;
                Hn_lds[col - 2*H_] = acc + bhn_r;
            }
        }
        __syncthreads();
        if (tid < H_) {
            float r = sigmoidf_(A_lds[tid]);
            float z = sigmoidf_(A_lds[H_ + tid]);
            float n = tanh_fast_(A_lds[2*H_ + tid] + r * Hn_lds[tid]);
            hj = n + z * (hj - n);            // (1-z)*n + z*h
            h_lds[tid] = hj;
        }
        __syncthreads();
        // fused output projection: out[b,t] = dot(h, Wo) + bo (wave 0 only)
        if (tid < 64) {
            float p = h_lds[tid]*wo0 + h_lds[tid+64]*wo1 + h_lds[tid+128]*wo2;
            if (tid < 8) p = fmaf(h_lds[192+tid], wo3, p);
            #pragma unroll
            for (int off = 32; off >= 1; off >>= 1)
                p += __shfl_xor(p, off, 64);
            if (tid == 0) outb[tc] = p + bov;
        }
    }
    if (tid < H_) hstate[b * H_ + tid] = hj;
}

extern "C" void kernel_launch(void* const* d_in, const int* in_sizes, int n_in,
                              void* d_out, int out_size, void* d_ws, size_t ws_size,
                              hipStream_t stream) {
    const float* x   = (const float*)d_in[0];
    const float* Wi  = (const float*)d_in[1];
    const float* bi  = (const float*)d_in[2];
    const float* Wh  = (const float*)d_in[3];
    const float* bhn = (const float*)d_in[4];
    const float* Wo  = (const float*)d_in[5];
    const float* bo  = (const float*)d_in[6];
    float* out = (float*)d_out;

    // Pick largest T-chunk whose gi buffer (+ h carry state) fits in ws.
    size_t hbytes = (size_t)B_ * H_ * sizeof(float);
    int TC = T_;
    while (TC > 64 && (size_t)B_ * TC * G_ * sizeof(float) + hbytes > ws_size) TC >>= 1;
    float* gi     = (float*)d_ws;
    float* hstate = (float*)((char*)d_ws + (size_t)B_ * TC * G_ * sizeof(float));

    int nchunks = T_ / TC;
    for (int c = 0; c < nchunks; ++c) {
        int t0 = c * TC;
        gi_kernel<<<dim3(B_ * TC / 64), dim3(640), 0, stream>>>(x, Wi, bi, gi, t0, TC);
        scan_kernel<<<dim3(B_), dim3(640), 0, stream>>>(gi, Wh, bhn, Wo, bo, out,
                                                        hstate, t0, TC, c == 0);
    }
}

// Round 2
// 5152.421 us; speedup vs baseline: 5.6601x; 5.6601x over previous
//
#include <hip/hip_runtime.h>
#include <cstdint>

#define B_  64
#define T_  4096
#define F_  100
#define H_  200
#define G_  600   // 3H

typedef _Float16 half2_t __attribute__((ext_vector_type(2)));

__device__ __forceinline__ float sigmoidf_(float x) {
    return 1.0f / (1.0f + __expf(-x));
}
__device__ __forceinline__ float tanh_fast_(float x) {
    float e = __expf(-2.0f * x);
    return (1.0f - e) / (1.0f + e);
}

__device__ __forceinline__ float fdot2_(half2_t a, half2_t b, float c) {
#if __has_builtin(__builtin_amdgcn_fdot2)
    return __builtin_amdgcn_fdot2(a, b, c, false);
#else
    return fmaf((float)a.x, (float)b.x, fmaf((float)a.y, (float)b.y, c));
#endif
}

// ---------------- Phase 0: pack Wh (f32, row-major [200,600]) -> half2 [100][600] ----------------
// whp[k*600 + c] = (Wh[2k][c], Wh[2k+1][c])
__global__ void prep_whp(const float* __restrict__ Wh, half2_t* __restrict__ whp) {
    int i = blockIdx.x * 256 + threadIdx.x;
    if (i < 100 * G_) {
        int k = i / G_, c = i - k * G_;
        half2_t v;
        v.x = (_Float16)Wh[(2 * k) * G_ + c];
        v.y = (_Float16)Wh[(2 * k + 1) * G_ + c];
        whp[i] = v;
    }
}

// ---------------- Phase 1: gi = x @ Wi + bi (fp32) ----------------
__global__ __launch_bounds__(640, 1)
void gi_kernel(const float* __restrict__ x, const float* __restrict__ Wi,
               const float* __restrict__ bi, float* __restrict__ gi,
               int t0, int TC) {
    __shared__ float xT[F_ * 68];
    int row0 = blockIdx.x * 64;
    int b    = row0 / TC;
    int tc0  = row0 - b * TC;
    const float* xrow = x + ((size_t)b * T_ + t0 + tc0) * F_;
    for (int i = threadIdx.x; i < 64 * F_; i += 640) {
        int r = i / F_, f = i - r * F_;
        xT[f * 68 + r] = xrow[i];
    }
    __syncthreads();
    int col = threadIdx.x < G_ ? threadIdx.x : G_ - 1;
    float acc[64];
    #pragma unroll
    for (int r = 0; r < 64; ++r) acc[r] = 0.f;
    for (int f = 0; f < F_; ++f) {
        float wi = Wi[f * G_ + col];
        const float4* xf = (const float4*)&xT[f * 68];
        #pragma unroll
        for (int q = 0; q < 16; ++q) {
            float4 v = xf[q];
            acc[4*q+0] = fmaf(v.x, wi, acc[4*q+0]);
            acc[4*q+1] = fmaf(v.y, wi, acc[4*q+1]);
            acc[4*q+2] = fmaf(v.z, wi, acc[4*q+2]);
            acc[4*q+3] = fmaf(v.w, wi, acc[4*q+3]);
        }
    }
    if (threadIdx.x < G_) {
        float bv = bi[col];
        float* grow = gi + (size_t)row0 * G_ + col;
        #pragma unroll 4
        for (int r = 0; r < 64; ++r) grow[(size_t)r * G_] = acc[r] + bv;
    }
}

// ---------------- Phase 2: sequential GRU scan ----------------
// 64 blocks (one per batch), 640 threads. Thread t owns Wh column t as 100 packed half2 regs.
__global__ __launch_bounds__(640, 1)
void scan_kernel(const float* __restrict__ gi, const half2_t* __restrict__ whp,
                 const float* __restrict__ bhn, _Float16* __restrict__ hs,
                 float* __restrict__ hstate, int TC, int first) {
    __shared__ __align__(16) _Float16 h_h[208];   // h in f16 (read via float4 broadcast)
    __shared__ float A_lds[G_];
    __shared__ float Hn_lds[H_];
    int b = blockIdx.x;
    int tid = threadIdx.x;
    int col = tid < G_ ? tid : G_ - 1;

    half2_t wh[100];   // 100 VGPRs of packed f16 weights — fits, no spill
    #pragma unroll
    for (int k = 0; k < 100; ++k) wh[k] = whp[k * G_ + col];   // coalesced
    float bhn_r = (col >= 2*H_) ? bhn[col - 2*H_] : 0.f;

    float hj = 0.f;
    if (tid < H_) {
        hj = first ? 0.f : hstate[b * H_ + tid];
        h_h[tid] = (_Float16)hj;
    }
    if (tid >= H_ && tid < 208) h_h[tid] = (_Float16)0.f;
    __syncthreads();

    const float* girow = gi + (size_t)b * TC * G_;
    _Float16* hsb = hs + (size_t)b * TC * H_;

    float g = girow[col];                        // prefetch step 0
    for (int tc = 0; tc < TC; ++tc) {
        float g_next = (tc + 1 < TC) ? girow[(size_t)(tc + 1) * G_ + col] : 0.f;  // prefetch
        // hh[col] = dot(h, Wh[:,col]) — h broadcast from LDS as f16, weights in regs
        float acc0 = 0.f, acc1 = 0.f;
        const float4* h4 = (const float4*)h_h;
        #pragma unroll
        for (int q = 0; q < 25; ++q) {
            float4 hv = h4[q];                   // 8 halves = 4 half2
            half2_t* hp = (half2_t*)&hv;
            acc0 = fdot2_(hp[0], wh[4*q+0], acc0);
            acc1 = fdot2_(hp[1], wh[4*q+1], acc1);
            acc0 = fdot2_(hp[2], wh[4*q+2], acc0);
            acc1 = fdot2_(hp[3], wh[4*q+3], acc1);
        }
        float acc = acc0 + acc1;
        if (tid < G_) {
            if (col < 2*H_) {
                A_lds[col] = g + acc;
            } else {
                A_lds[col] = g;
                Hn_lds[col - 2*H_] = acc + bhn_r;
            }
        }
        __syncthreads();
        if (tid < H_) {
            float r = sigmoidf_(A_lds[tid]);
            float z = sigmoidf_(A_lds[H_ + tid]);
            float n = tanh_fast_(A_lds[2*H_ + tid] + r * Hn_lds[tid]);
            hj = n + z * (hj - n);
            h_h[tid] = (_Float16)hj;
            hsb[(size_t)tc * H_ + tid] = (_Float16)hj;   // fire-and-forget store
        }
        __syncthreads();
        g = g_next;
    }
    if (tid < H_) hstate[b * H_ + tid] = hj;
}

// ---------------- Phase 3: out = hs @ Wo + bo ----------------
__global__ __launch_bounds__(256, 4)
void outproj_kernel(const _Float16* __restrict__ hs, const float* __restrict__ Wo,
                    const float* __restrict__ bo, float* __restrict__ out,
                    int t0, int TC) {
    int r = blockIdx.x * 256 + threadIdx.x;
    if (r >= B_ * TC) return;
    int b = r / TC, tc = r - b * TC;
    const float4* h4 = (const float4*)(hs + (size_t)r * H_);
    float acc = 0.f;
    #pragma unroll
    for (int q = 0; q < 25; ++q) {
        float4 v = h4[q];
        const _Float16* hp = (const _Float16*)&v;
        #pragma unroll
        for (int j = 0; j < 8; ++j)
            acc = fmaf((float)hp[j], Wo[q * 8 + j], acc);
    }
    out[(size_t)b * T_ + t0 + tc] = acc + bo[0];
}

extern "C" void kernel_launch(void* const* d_in, const int* in_sizes, int n_in,
                              void* d_out, int out_size, void* d_ws, size_t ws_size,
                              hipStream_t stream) {
    const float* x   = (const float*)d_in[0];
    const float* Wi  = (const float*)d_in[1];
    const float* bi  = (const float*)d_in[2];
    const float* Wh  = (const float*)d_in[3];
    const float* bhn = (const float*)d_in[4];
    const float* Wo  = (const float*)d_in[5];
    const float* bo  = (const float*)d_in[6];
    float* out = (float*)d_out;

    const size_t hstate_b = (size_t)B_ * H_ * sizeof(float);
    const size_t whp_b    = (size_t)100 * G_ * sizeof(half2_t);
    // ws layout: [gi: B*TC*G*4][hs: B*TC*H*2][hstate][whp]
    int TC = T_;
    while (TC > 64 &&
           (size_t)B_ * TC * (G_ * 4 + H_ * 2) + hstate_b + whp_b > ws_size)
        TC >>= 1;
    char* p = (char*)d_ws;
    float*    gi     = (float*)p;            p += (size_t)B_ * TC * G_ * sizeof(float);
    _Float16* hsbuf  = (_Float16*)p;         p += (size_t)B_ * TC * H_ * sizeof(_Float16);
    float*    hstate = (float*)p;            p += hstate_b;
    half2_t*  whp    = (half2_t*)p;

    prep_whp<<<dim3((100 * G_ + 255) / 256), dim3(256), 0, stream>>>(Wh, whp);

    int nchunks = T_ / TC;
    for (int c = 0; c < nchunks; ++c) {
        int t0 = c * TC;
        gi_kernel<<<dim3(B_ * TC / 64), dim3(640), 0, stream>>>(x, Wi, bi, gi, t0, TC);
        scan_kernel<<<dim3(B_), dim3(640), 0, stream>>>(gi, whp, bhn, hsbuf,
                                                        hstate, TC, c == 0);
        outproj_kernel<<<dim3((B_ * TC + 255) / 256), dim3(256), 0, stream>>>(
            hsbuf, Wo, bo, out, t0, TC);
    }
}